// Round 2
// baseline (95255.109 us; speedup 1.0000x reference)
//
#include <hip/hip_runtime.h>
#include <hip/hip_bf16.h>
#include <math.h>

// ---------------------------------------------------------------------------
// TextGenerationModel: 2-layer LSTM (B=64,S=512,V=128,H=1024) + FC + logsoftmax
// Round 2: fp32 correctness baseline with MINIMAL workspace (~2 MB).
//   Round-1 postmortem: needed 673 MB of d_ws (xw precompute + h history);
//   ws_size is evidently smaller -> GPU page fault -> core dump.
//   Now: per-timestep fused pipeline, no sequence-sized scratch.
//     per t: gates0 = x_t*Wih0^T + h0*Whh0^T + b   (fused 2-operand GEMM)
//            (h0,c0) update
//            gates1 = h0*Wih1^T + h1*Whh1^T + b
//            (h1,c1) update
//            out[:,t,:] = h1*Wfc^T + bfc
//   final: in-place log_softmax on d_out.
// Workspace floats: h0,c0,h1,c1 (64*1024 each) + gates (64*4096) = 2.0 MB.
// ---------------------------------------------------------------------------

#define S_LEN 512
#define B_SZ  64
#define V_SZ  128
#define H_SZ  1024
#define G4    (4 * H_SZ)   // 4096

// ===================== fused two-operand GEMM ==============================
// out[b,n] = bias0[n] (+bias1[n]) + sum_k A1[b,k]*W1[n,k] + sum_k A2[b,k]*W2[n,k]
// A1 rows strided by a1StrideB (K1 contiguous); W1 row-major (N,K1).
// A2 rows contiguous stride K2; W2 row-major (N,K2). K2==0 -> skip pass 2.
// out row b at out + b*oStrideB (N contiguous).
// M=64 fixed; tiles 32x32, 256 threads, grid (2, N/32).
#define TM 32
#define TN 32
#define TK 32
__global__ __launch_bounds__(256) void fused_gemm(
    const float* __restrict__ A1, long a1StrideB, int K1, const float* __restrict__ W1,
    const float* __restrict__ A2, int K2, const float* __restrict__ W2,
    const float* __restrict__ bias0, const float* __restrict__ bias1,
    float* __restrict__ out, long oStrideB)
{
    __shared__ float As[TK][TM + 1];
    __shared__ float Ws[TK][TN + 1];
    const int tid = threadIdx.x;
    const int m0 = blockIdx.x * TM;
    const int n0 = blockIdx.y * TN;
    const int tx = tid & 15, ty = tid >> 4;   // 2x2 outputs per thread

    float acc[2][2] = {};

    #pragma unroll 1
    for (int pass = 0; pass < 2; ++pass) {
        const float* A = pass ? A2 : A1;
        const float* W = pass ? W2 : W1;
        const int K    = pass ? K2 : K1;
        const long aS  = pass ? (long)K2 : a1StrideB;
        if (K == 0) continue;
        #pragma unroll 1
        for (int k0 = 0; k0 < K; k0 += TK) {
            int row = tid >> 3, col = (tid & 7) * 4;  // 32 rows x 32 cols, float4
            float4 av = *(const float4*)(A + (long)(m0 + row) * aS + k0 + col);
            As[col + 0][row] = av.x; As[col + 1][row] = av.y;
            As[col + 2][row] = av.z; As[col + 3][row] = av.w;
            float4 wv = *(const float4*)(W + (long)(n0 + row) * K + k0 + col);
            Ws[col + 0][row] = wv.x; Ws[col + 1][row] = wv.y;
            Ws[col + 2][row] = wv.z; Ws[col + 3][row] = wv.w;
            __syncthreads();
            #pragma unroll
            for (int kk = 0; kk < TK; ++kk) {
                float a0 = As[kk][ty * 2],     a1v = As[kk][ty * 2 + 1];
                float w0 = Ws[kk][tx * 2],     w1v = Ws[kk][tx * 2 + 1];
                acc[0][0] += a0 * w0;  acc[0][1] += a0 * w1v;
                acc[1][0] += a1v * w0; acc[1][1] += a1v * w1v;
            }
            __syncthreads();
        }
    }

    #pragma unroll
    for (int i = 0; i < 2; ++i) {
        int b = m0 + ty * 2 + i;
        #pragma unroll
        for (int j = 0; j < 2; ++j) {
            int n = n0 + tx * 2 + j;
            float bs = bias0[n] + (bias1 ? bias1[n] : 0.0f);
            out[(long)b * oStrideB + n] = acc[i][j] + bs;
        }
    }
}

// ========================= LSTM elementwise ================================
__device__ __forceinline__ float sigmoid_f(float x) { return 1.0f / (1.0f + __expf(-x)); }

__global__ __launch_bounds__(256) void lstm_update(
    const float* __restrict__ gates,  // (64, 4096) order i,f,g,o
    float* __restrict__ c,            // (64, 1024) in-place
    float* __restrict__ h)            // (64, 1024) in-place (read by prior GEMM, done)
{
    int idx = blockIdx.x * 256 + threadIdx.x;      // 0..65535
    int b = idx >> 10, j = idx & 1023;
    const float* g = gates + b * G4;
    float iv = sigmoid_f(g[j]);
    float fv = sigmoid_f(g[H_SZ + j]);
    float gv = tanhf(g[2 * H_SZ + j]);
    float ov = sigmoid_f(g[3 * H_SZ + j]);
    float cv = fv * c[idx] + iv * gv;
    c[idx] = cv;
    h[idx] = ov * tanhf(cv);
}

// ========================= log_softmax (V=128) =============================
__global__ __launch_bounds__(256) void log_softmax_rows(float* __restrict__ out)
{
    int row = blockIdx.x * 4 + (threadIdx.x >> 6);   // one wave64 per row
    int lane = threadIdx.x & 63;
    float* p = out + (long)row * V_SZ;
    float a = p[lane], b = p[lane + 64];
    float mx = fmaxf(a, b);
    #pragma unroll
    for (int o = 32; o > 0; o >>= 1) mx = fmaxf(mx, __shfl_xor(mx, o));
    float se = __expf(a - mx) + __expf(b - mx);
    #pragma unroll
    for (int o = 32; o > 0; o >>= 1) se += __shfl_xor(se, o);
    float ls = mx + logf(se);
    p[lane] = a - ls;
    p[lane + 64] = b - ls;
}

// =============================== launcher ==================================
extern "C" void kernel_launch(void* const* d_in, const int* in_sizes, int n_in,
                              void* d_out, int out_size, void* d_ws, size_t ws_size,
                              hipStream_t stream)
{
    const float* x    = (const float*)d_in[0];
    const float* Wih0 = (const float*)d_in[1];
    const float* Whh0 = (const float*)d_in[2];
    const float* bih0 = (const float*)d_in[3];
    const float* bhh0 = (const float*)d_in[4];
    const float* Wih1 = (const float*)d_in[5];
    const float* Whh1 = (const float*)d_in[6];
    const float* bih1 = (const float*)d_in[7];
    const float* bhh1 = (const float*)d_in[8];
    const float* Wfc  = (const float*)d_in[9];
    const float* bfc  = (const float*)d_in[10];
    float* out = (float*)d_out;

    const size_t BH = (size_t)B_SZ * H_SZ;           // 65536
    float* h0 = (float*)d_ws;
    float* c0 = h0 + BH;
    float* h1 = c0 + BH;
    float* c1 = h1 + BH;
    float* g  = c1 + BH;                             // 64*4096 = 262144

    hipMemsetAsync(h0, 0, 4 * BH * sizeof(float), stream);  // h0,c0,h1,c1 -> 0

    dim3 gGate(B_SZ / TM, G4 / TN);     // (2, 128)
    dim3 gFc(B_SZ / TM, V_SZ / TN);     // (2, 4)

    for (int t = 0; t < S_LEN; ++t) {
        // layer 0: gates = x_t*Wih0^T + h0*Whh0^T + (bih0+bhh0)
        fused_gemm<<<gGate, 256, 0, stream>>>(
            x + (size_t)t * V_SZ, (long)S_LEN * V_SZ, V_SZ, Wih0,
            h0, H_SZ, Whh0, bih0, bhh0, g, (long)G4);
        lstm_update<<<BH / 256, 256, 0, stream>>>(g, c0, h0);

        // layer 1: gates = h0*Wih1^T + h1*Whh1^T + (bih1+bhh1)
        fused_gemm<<<gGate, 256, 0, stream>>>(
            h0, (long)H_SZ, H_SZ, Wih1,
            h1, H_SZ, Whh1, bih1, bhh1, g, (long)G4);
        lstm_update<<<BH / 256, 256, 0, stream>>>(g, c1, h1);

        // logits_t: out[:,t,:] = h1*Wfc^T + bfc
        fused_gemm<<<gFc, 256, 0, stream>>>(
            h1, (long)H_SZ, H_SZ, Wfc,
            nullptr, 0, nullptr, bfc, nullptr,
            out + (size_t)t * V_SZ, (long)S_LEN * V_SZ);
    }

    // in-place log_softmax over last dim (V=128), all B*S rows
    log_softmax_rows<<<S_LEN * B_SZ / 4, 256, 0, stream>>>(out);
}

// Round 3
// 12250.498 us; speedup vs baseline: 7.7756x; 7.7756x over previous
//
#include <hip/hip_runtime.h>
#include <hip/hip_bf16.h>
#include <math.h>

// ---------------------------------------------------------------------------
// Round 3: bf16 MFMA, fused gates+LSTM-update epilogue, layer-staggered
// one-kernel-per-step pipeline (layer0(t) || layer1(t-1) || fc+logsmax(t-2)).
// ws: bf16 weights 26.4MB + h0/h1 double-buffers (bf16) + c0/c1 (fp32) = 27.5MB
// ---------------------------------------------------------------------------

#define S_LEN 512
#define B_SZ  64
#define V_SZ  128
#define H_SZ  1024
#define G4    4096
#define BH    (B_SZ * H_SZ)   // 65536

typedef unsigned short u16x8 __attribute__((ext_vector_type(8)));
typedef __bf16         bf16x8 __attribute__((ext_vector_type(8)));
typedef float          f32x4  __attribute__((ext_vector_type(4)));

__device__ __forceinline__ unsigned short f2bf(float f) {
    unsigned int u = __float_as_uint(f);
    u += 0x7fffu + ((u >> 16) & 1u);            // RNE, finite inputs
    return (unsigned short)(u >> 16);
}

__device__ __forceinline__ f32x4 mfma16(u16x8 a, u16x8 b, f32x4 c) {
    return __builtin_amdgcn_mfma_f32_16x16x32_bf16(
        __builtin_bit_cast(bf16x8, a), __builtin_bit_cast(bf16x8, b), c, 0, 0, 0);
}

// fp32 -> bf16 conversion, 4 elems/thread
__global__ __launch_bounds__(256) void cvt_kernel(const float* __restrict__ s,
                                                  unsigned short* __restrict__ d, int n)
{
    int i = (blockIdx.x * 256 + threadIdx.x) * 4;
    if (i >= n) return;
    float4 v = *(const float4*)(s + i);
    ushort4 o;
    o.x = f2bf(v.x); o.y = f2bf(v.y); o.z = f2bf(v.z); o.w = f2bf(v.w);
    *(ushort4*)(d + i) = o;
}

// ---------------------------------------------------------------------------
// step kernel: grid 132 blocks x 256 threads
//  blocks   0..63 : layer0, step t      (16 j-cols, all 4 gates, fused update)
//  blocks  64..127: layer1, step t-1
//  blocks 128..131: fc + log_softmax, step t-2 (16 batch rows each)
// ---------------------------------------------------------------------------
__global__ __launch_bounds__(256) void step_kernel(
    int t,
    const float* __restrict__ x,
    const unsigned short* __restrict__ Wih0, const unsigned short* __restrict__ Whh0,
    const unsigned short* __restrict__ Wih1, const unsigned short* __restrict__ Whh1,
    const unsigned short* __restrict__ Wfc,
    const float* __restrict__ bih0, const float* __restrict__ bhh0,
    const float* __restrict__ bih1, const float* __restrict__ bhh1,
    const float* __restrict__ bfc,
    unsigned short* __restrict__ h0b, unsigned short* __restrict__ h1b,
    float* __restrict__ c0, float* __restrict__ c1,
    float* __restrict__ out)
{
    __shared__ unsigned short sA[64 * 40];    // rows padded to 80B: 2-way bank alias only
    __shared__ unsigned short sW[128 * 40];
    __shared__ float sLg[16][132];

    const int bid  = blockIdx.x;
    const int tid  = threadIdx.x;
    const int wave = tid >> 6, lane = tid & 63;
    const int col  = lane & 15, kg = lane >> 4;

    if (bid < 128) {
        // ======================= layer job =======================
        const bool L1 = (bid >= 64);
        if (L1 ? (t < 1 || t > S_LEN) : (t >= S_LEN)) return;
        const int j0 = (bid & 63) * 16;

        const float* A1f; const unsigned short* A1b; long a1s; int K1;
        const unsigned short *W1, *W2, *A2;
        const float *bi, *bh; float* cst; unsigned short* hout;
        if (!L1) {
            A1f = x + (long)t * V_SZ; A1b = nullptr; a1s = (long)S_LEN * V_SZ; K1 = V_SZ;
            W1 = Wih0; W2 = Whh0;
            A2 = h0b + ((t & 1) ^ 1) * BH;          // h0[t-1]
            bi = bih0; bh = bhh0; cst = c0;
            hout = h0b + (t & 1) * BH;              // h0[t]
        } else {
            const int s = t - 1;
            A1f = nullptr; A1b = h0b + (s & 1) * BH; a1s = H_SZ; K1 = H_SZ;  // h0[s]
            W1 = Wih1; W2 = Whh1;
            A2 = h1b + ((s & 1) ^ 1) * BH;          // h1[s-1]
            bi = bih1; bh = bhh1; cst = c1;
            hout = h1b + (s & 1) * BH;              // h1[s]
        }

        const int ar  = tid >> 2, ako = (tid & 3) * 8;          // stage: 64 rows x 32k, 8 elems/thr
        const int wrow = ((ar >> 4) << 10) + j0 + (ar & 15);    // gate-grouped W row

        f32x4 acc[4] = {{0,0,0,0},{0,0,0,0},{0,0,0,0},{0,0,0,0}};

        for (int pass = 0; pass < 2; ++pass) {
            const float* Af          = pass ? nullptr : A1f;
            const unsigned short* Ab = pass ? A2 : A1b;
            const long as_           = pass ? (long)H_SZ : a1s;
            const unsigned short* W  = pass ? W2 : W1;
            const int K              = pass ? H_SZ : K1;
            const int nc             = K >> 5;

            auto loadA = [&](int k0) -> u16x8 {
                if (Af) {
                    const float* p = Af + (long)ar * as_ + k0 + ako;
                    float4 u = *(const float4*)p;
                    float4 v = *(const float4*)(p + 4);
                    u16x8 r;
                    r[0] = f2bf(u.x); r[1] = f2bf(u.y); r[2] = f2bf(u.z); r[3] = f2bf(u.w);
                    r[4] = f2bf(v.x); r[5] = f2bf(v.y); r[6] = f2bf(v.z); r[7] = f2bf(v.w);
                    return r;
                }
                return *(const u16x8*)(Ab + (long)ar * as_ + k0 + ako);
            };
            auto loadW = [&](int k0) -> u16x8 {
                return *(const u16x8*)(W + (long)wrow * K + k0 + ako);
            };

            u16x8 ra = loadA(0), rw = loadW(0);
            for (int c = 0; c < nc; ++c) {
                __syncthreads();                              // prev compute done
                *(u16x8*)(sA + ar * 40 + ako) = ra;
                *(u16x8*)(sW + ar * 40 + ako) = rw;
                __syncthreads();                              // tile ready
                if (c + 1 < nc) { ra = loadA((c + 1) * 32); rw = loadW((c + 1) * 32); }
                u16x8 af = *(const u16x8*)(sA + (wave * 16 + col) * 40 + kg * 8);
                #pragma unroll
                for (int nt = 0; nt < 4; ++nt) {
                    u16x8 bf_ = *(const u16x8*)(sW + (nt * 16 + col) * 40 + kg * 8);
                    acc[nt] = mfma16(af, bf_, acc[nt]);
                }
            }
        }

        // fused LSTM update: lane holds gates i,f,g,o (=acc[0..3]) for col j0+col,
        // rows m = wave*16 + kg*4 + r
        {
            const int jj = j0 + col;
            const float bii = bi[jj]            + bh[jj];
            const float bif = bi[H_SZ + jj]     + bh[H_SZ + jj];
            const float big = bi[2 * H_SZ + jj] + bh[2 * H_SZ + jj];
            const float bio = bi[3 * H_SZ + jj] + bh[3 * H_SZ + jj];
            #pragma unroll
            for (int r = 0; r < 4; ++r) {
                const int m = wave * 16 + kg * 4 + r;
                const float ip = acc[0][r] + bii;
                const float fp = acc[1][r] + bif;
                const float gp = acc[2][r] + big;
                const float op = acc[3][r] + bio;
                const float iv = 1.f / (1.f + expf(-ip));
                const float fv = 1.f / (1.f + expf(-fp));
                const float gv = tanhf(gp);
                const float ov = 1.f / (1.f + expf(-op));
                const long ci = (long)m * H_SZ + jj;
                const float cv = fv * cst[ci] + iv * gv;
                cst[ci] = cv;
                hout[ci] = f2bf(ov * tanhf(cv));
            }
        }
        return;
    }

    // ======================= fc + log_softmax job =======================
    {
        if (t < 2) return;
        const int s = t - 2;
        const unsigned short* h1 = h1b + (s & 1) * BH;
        const int m0 = (bid - 128) * 16;

        f32x4 acc[2] = {{0,0,0,0},{0,0,0,0}};
        const int ar = tid >> 2, ako = (tid & 3) * 8;

        auto loadA = [&](int k0) -> u16x8 {
            return *(const u16x8*)(h1 + (long)(m0 + ar) * H_SZ + k0 + ako);
        };
        auto loadW = [&](int k0, int rofs) -> u16x8 {
            return *(const u16x8*)(Wfc + (long)(ar + rofs) * H_SZ + k0 + ako);
        };

        u16x8 ra = {}; u16x8 rw0, rw1;
        if (tid < 64) ra = loadA(0);
        rw0 = loadW(0, 0); rw1 = loadW(0, 64);
        for (int c = 0; c < H_SZ / 32; ++c) {
            __syncthreads();
            if (tid < 64) *(u16x8*)(sA + ar * 40 + ako) = ra;
            *(u16x8*)(sW + ar * 40 + ako)        = rw0;
            *(u16x8*)(sW + (ar + 64) * 40 + ako) = rw1;
            __syncthreads();
            if (c + 1 < H_SZ / 32) {
                if (tid < 64) ra = loadA((c + 1) * 32);
                rw0 = loadW((c + 1) * 32, 0); rw1 = loadW((c + 1) * 32, 64);
            }
            u16x8 af = *(const u16x8*)(sA + col * 40 + kg * 8);
            #pragma unroll
            for (int nt = 0; nt < 2; ++nt) {
                u16x8 bf_ = *(const u16x8*)(sW + (wave * 32 + nt * 16 + col) * 40 + kg * 8);
                acc[nt] = mfma16(af, bf_, acc[nt]);
            }
        }
        #pragma unroll
        for (int nt = 0; nt < 2; ++nt)
            #pragma unroll
            for (int r = 0; r < 4; ++r) {
                const int m = kg * 4 + r, n = wave * 32 + nt * 16 + col;
                sLg[m][n] = acc[nt][r] + bfc[n];
            }
        __syncthreads();
        const int row = tid >> 4, sub = tid & 15;   // 16 threads per row
        float vals[8]; float mx = -1e30f;
        #pragma unroll
        for (int q = 0; q < 8; ++q) { vals[q] = sLg[row][sub * 8 + q]; mx = fmaxf(mx, vals[q]); }
        #pragma unroll
        for (int o = 1; o < 16; o <<= 1) mx = fmaxf(mx, __shfl_xor(mx, o));
        float se = 0.f;
        #pragma unroll
        for (int q = 0; q < 8; ++q) se += expf(vals[q] - mx);
        #pragma unroll
        for (int o = 1; o < 16; o <<= 1) se += __shfl_xor(se, o);
        const float ls = mx + logf(se);
        float* op = out + (long)(m0 + row) * S_LEN * V_SZ + (long)s * V_SZ + sub * 8;
        #pragma unroll
        for (int q = 0; q < 8; ++q) op[q] = vals[q] - ls;
    }
}

// =============================== launcher ==================================
extern "C" void kernel_launch(void* const* d_in, const int* in_sizes, int n_in,
                              void* d_out, int out_size, void* d_ws, size_t ws_size,
                              hipStream_t stream)
{
    const float* x    = (const float*)d_in[0];
    const float* Wih0 = (const float*)d_in[1];
    const float* Whh0 = (const float*)d_in[2];
    const float* bih0 = (const float*)d_in[3];
    const float* bhh0 = (const float*)d_in[4];
    const float* Wih1 = (const float*)d_in[5];
    const float* Whh1 = (const float*)d_in[6];
    const float* bih1 = (const float*)d_in[7];
    const float* bhh1 = (const float*)d_in[8];
    const float* Wfc  = (const float*)d_in[9];
    const float* bfc  = (const float*)d_in[10];
    float* out = (float*)d_out;

    unsigned short* wih0 = (unsigned short*)d_ws;              // 4096*128
    unsigned short* whh0 = wih0 + (size_t)G4 * V_SZ;           // 4096*1024
    unsigned short* wih1 = whh0 + (size_t)G4 * H_SZ;
    unsigned short* whh1 = wih1 + (size_t)G4 * H_SZ;
    unsigned short* wfc  = whh1 + (size_t)G4 * H_SZ;           // 128*1024
    unsigned short* h0b  = wfc  + (size_t)V_SZ * H_SZ;         // 2 slots
    unsigned short* h1b  = h0b + 2 * (size_t)BH;
    float* c0 = (float*)(h1b + 2 * (size_t)BH);
    float* c1 = c0 + BH;
    // total: 27.5 MB

    auto cvt = [&](const float* s, unsigned short* d, int n) {
        cvt_kernel<<<(n / 4 + 255) / 256, 256, 0, stream>>>(s, d, n);
    };
    cvt(Wih0, wih0, G4 * V_SZ);
    cvt(Whh0, whh0, G4 * H_SZ);
    cvt(Wih1, wih1, G4 * H_SZ);
    cvt(Whh1, whh1, G4 * H_SZ);
    cvt(Wfc,  wfc,  V_SZ * H_SZ);
    hipMemsetAsync(h0b, 0, (size_t)4 * BH * sizeof(unsigned short), stream);
    hipMemsetAsync(c0,  0, (size_t)2 * BH * sizeof(float), stream);

    for (int t = 0; t <= S_LEN + 1; ++t)
        step_kernel<<<132, 256, 0, stream>>>(t, x, wih0, whh0, wih1, whh1, wfc,
            bih0, bhh0, bih1, bhh1, bfc, h0b, h1b, c0, c1, out);
}